// Round 12
// baseline (349.677 us; speedup 1.0000x reference)
//
#include <hip/hip_runtime.h>

#define N_NODES 50000
#define E_EDGES 800000
#define D 256
#define L 128
#define CAP 64   // max in-degree bucket capacity; Poisson(16) tail => P(overflow) ~ 1e-19
#define ZLD 264  // Zs LDS row stride (elems): 256 + 8 pad -> spreads banks, keeps 16B align

typedef __attribute__((ext_vector_type(8))) short bf16x8;
typedef __attribute__((ext_vector_type(4))) float f32x4;

__device__ __forceinline__ float bf2f(unsigned short u) {
    union { unsigned int i; float f; } v; v.i = ((unsigned int)u) << 16; return v.f;
}
__device__ __forceinline__ unsigned short f2bf(float f) {  // round-to-nearest-even
    union { float f; unsigned int i; } v; v.f = f;
    unsigned int r = v.i + 0x7fffu + ((v.i >> 16) & 1u);
    return (unsigned short)(r >> 16);
}

// Setup with LDS-tiled transpose (coalesced both sides). Blocks 0..63: W1
// (hi+lo); 64..127: Wcat=[Wmu|Wlv] (hi only — head GEMM is single-term;
// block 64 also fills bcat); rest zero cursor.
__global__ __launch_bounds__(256) void setup_t(
    const float* __restrict__ W1, const float* __restrict__ Wmu,
    const float* __restrict__ Wlv, const float* __restrict__ bmu,
    const float* __restrict__ blv,
    unsigned short* __restrict__ W1h, unsigned short* __restrict__ W1l,
    unsigned short* __restrict__ Wch,
    float* __restrict__ bcat, int* __restrict__ cursor) {
    int b = blockIdx.x, t = threadIdx.x;
    if (b < 128) {
        __shared__ float tile[32][33];          // +1 pad: conflict-free transpose
        int m = b >> 6;                         // 0: W1, 1: Wcat
        int ti = b & 63;
        int k0 = (ti >> 3) * 32, n0 = (ti & 7) * 32;
        int rr = t >> 5, cc = t & 31;           // 8 rows x 32 cols per pass
#pragma unroll
        for (int p = 0; p < 4; ++p) {           // load 32x32 fp32, coalesced in n
            int kk = p * 8 + rr;
            int k = k0 + kk, n = n0 + cc;
            float w;
            if (m == 0) w = W1[k * 256 + n];
            else        w = (n < 128) ? Wmu[k * 128 + n] : Wlv[k * 128 + (n - 128)];
            tile[kk][cc] = w;
        }
        __syncthreads();
#pragma unroll
        for (int p = 0; p < 4; ++p) {           // store [n][k], coalesced in k
            int nn = p * 8 + rr;
            float w = tile[cc][nn];
            unsigned short h = f2bf(w);
            int n = n0 + nn, k = k0 + cc;
            if (m == 0) {
                W1h[n * 256 + k] = h;
                W1l[n * 256 + k] = f2bf(w - bf2f(h));
            } else {
                Wch[n * 256 + k] = h;
            }
        }
        if (b == 64) bcat[t] = (t < 128) ? bmu[t] : blv[t - 128];
    } else {
        int i = (b - 128) * 256 + t;
        if (i < N_NODES) cursor[i] = 0;
    }
}

// FUSED: layer-1 GEMM + bucket build, co-scheduled in one grid (r8-verified
// best arrangement: ~73-80 us). Blocks with bid%9==0 (exactly 391) run a
// 128-row GEMM tile; the other 3125 blocks each process 256 edges of the
// atomic bucket build. Bucket entries ushort (src < 65536).
__global__ __launch_bounds__(256, 2) void gemm1_fill(
    const float* __restrict__ A,
    const unsigned short* __restrict__ Bth, const unsigned short* __restrict__ Btl,
    unsigned short* __restrict__ Hout, int M,
    const int* __restrict__ src, const int* __restrict__ dst,
    int* __restrict__ cursor, unsigned short* __restrict__ bucket)
{
    __shared__ unsigned short Ash[128 * 32];   // 8 KB
    __shared__ unsigned short Asl[128 * 32];   // 8 KB
    __shared__ unsigned short Bsh[256 * 32];   // 16 KB
    __shared__ unsigned short Bsl[256 * 32];   // 16 KB
    const int bid = blockIdx.x;
    const int qb = bid / 9, rb = bid - qb * 9;
    const int t = threadIdx.x;

    if (rb != 0) {
        // ---- fill role: 256 edges ----
        int e = (bid - qb - 1) * 256 + t;      // bijective onto [0, 800000)
        if (e < E_EDGES) {
            int d = dst[e];
            int pos = atomicAdd(&cursor[d], 1);
            if (pos < CAP) bucket[d * CAP + pos] = (unsigned short)src[e];
        }
        return;
    }

    // ---- GEMM role: tile qb (0..390), r4-verified structure ----
    const int lane = t & 63, wave = t >> 6;
    const int m_ = lane & 15, q = lane >> 4;
    const int wr = wave >> 1, wc = wave & 1;   // 2x2 wave grid
    const int row0 = qb * 128;
    const int sr = t >> 2;                     // staging row 0..63
    const int sc = t & 3;                      // staging chunk 0..3

    f32x4 acc[4][8];
    const f32x4 zf = {0.f, 0.f, 0.f, 0.f};
#pragma unroll
    for (int rs = 0; rs < 4; ++rs)
#pragma unroll
        for (int nt = 0; nt < 8; ++nt) acc[rs][nt] = zf;

    for (int ks = 0; ks < 8; ++ks) {
        const int k0 = ks * 32;
        bf16x8 gbh[4], gbl[4];
#pragma unroll
        for (int i = 0; i < 4; ++i) {
            int n = sr + i * 64;
            gbh[i] = *(const bf16x8*)(Bth + n * 256 + k0 + sc * 8);
            gbl[i] = *(const bf16x8*)(Btl + n * 256 + k0 + sc * 8);
        }
        float4 ga0[2], ga1[2];
#pragma unroll
        for (int p = 0; p < 2; ++p) {
            int r = row0 + p * 64 + sr; if (r >= M) r = M - 1;
            const float* Xp = A + (size_t)r * 256 + k0 + sc * 8;
            ga0[p] = *(const float4*)Xp;
            ga1[p] = *(const float4*)(Xp + 4);
        }
        __syncthreads();
#pragma unroll
        for (int p = 0; p < 2; ++p) {
            int lr = p * 64 + sr;
            int cc = (sc ^ ((lr >> 1) & 3)) * 8;
            float af[8] = {ga0[p].x, ga0[p].y, ga0[p].z, ga0[p].w,
                           ga1[p].x, ga1[p].y, ga1[p].z, ga1[p].w};
            bf16x8 h, l;
#pragma unroll
            for (int j = 0; j < 8; ++j) {
                unsigned short hh = f2bf(af[j]);
                h[j] = (short)hh;
                l[j] = (short)f2bf(af[j] - bf2f(hh));
            }
            *(bf16x8*)&Ash[lr * 32 + cc] = h;
            *(bf16x8*)&Asl[lr * 32 + cc] = l;
        }
#pragma unroll
        for (int i = 0; i < 4; ++i) {
            int n = sr + i * 64;
            int cc = (sc ^ ((n >> 1) & 3)) * 8;
            *(bf16x8*)&Bsh[n * 32 + cc] = gbh[i];
            *(bf16x8*)&Bsl[n * 32 + cc] = gbl[i];
        }
        __syncthreads();
        bf16x8 ah[4], al[4];
#pragma unroll
        for (int rs = 0; rs < 4; ++rs) {
            int r = wr * 64 + rs * 16 + m_;
            int cc = (q ^ ((r >> 1) & 3)) * 8;
            ah[rs] = *(const bf16x8*)&Ash[r * 32 + cc];
            al[rs] = *(const bf16x8*)&Asl[r * 32 + cc];
        }
#pragma unroll
        for (int nt = 0; nt < 8; ++nt) {
            int n = wc * 128 + nt * 16 + m_;
            int cr = (q ^ ((n >> 1) & 3)) * 8;
            bf16x8 bh = *(const bf16x8*)&Bsh[n * 32 + cr];
            bf16x8 bl = *(const bf16x8*)&Bsl[n * 32 + cr];
#pragma unroll
            for (int rs = 0; rs < 4; ++rs) {
                acc[rs][nt] = __builtin_amdgcn_mfma_f32_16x16x32_bf16(ah[rs], bh, acc[rs][nt], 0, 0, 0);
                acc[rs][nt] = __builtin_amdgcn_mfma_f32_16x16x32_bf16(ah[rs], bl, acc[rs][nt], 0, 0, 0);
                acc[rs][nt] = __builtin_amdgcn_mfma_f32_16x16x32_bf16(al[rs], bh, acc[rs][nt], 0, 0, 0);
            }
        }
    }
    // epilogue: C/D layout col=lane&15, row=(lane>>4)*4+reg  [m89/m91 verified]
#pragma unroll
    for (int rs = 0; rs < 4; ++rs) {
        int rbase = row0 + wr * 64 + rs * 16 + q * 4;
#pragma unroll
        for (int rr = 0; rr < 4; ++rr) {
            int grow = rbase + rr;
            if (grow >= M) continue;
#pragma unroll
            for (int nt = 0; nt < 8; ++nt) {
                int gcol = wc * 128 + nt * 16 + m_;
                Hout[(size_t)grow * 256 + gcol] = f2bf(acc[rs][nt][rr]);
            }
        }
    }
}

// FUSED mode-0 gather + head GEMM: per block of 8 nodes, gather H -> agg,
// Z = relu(agg + b1) -> LDS (never global), then mini-GEMM T = Z @ Wc_hi
// with A-frags from LDS (rows m_&7; rows 8-15 duplicate, outputs discarded)
// and B-frags streamed from L2-resident Wch. Replaces gemm_bf16 (~55 us,
// LDS-bound + 1.53 blk/CU imbalanced) and kills 51 MB of Z global traffic.
// Math bit-identical to the r8 path (same bf16 roundings, single-term B).
__global__ __launch_bounds__(256) void gather_gemm(
    const unsigned short* __restrict__ Hs,
    const unsigned short* __restrict__ bucket, const int* __restrict__ cnt_,
    const float* __restrict__ bias,
    const unsigned short* __restrict__ Wch,
    unsigned short* __restrict__ Tout)
{
    __shared__ unsigned short Zs[8 * ZLD];    // 4.2 KB
    const int t = threadIdx.x;
    const int lane = t & 63;
    const int hl = lane & 31;                 // lane within half-wave
    const int bb = lane & 32;                 // half-select for shfl index
    const int lrow = t >> 5;                  // local node row 0..7
    const int nb0 = blockIdx.x * 8;
    const int node = nb0 + lrow;
    const int col = hl * 8;                   // 8 bf16 columns per lane
    int raw = cnt_[node];
    float dn = rsqrtf((float)raw + 1.0f);
    int cnt = raw > CAP ? CAP : raw;

    // preload: half-lane j owns edge j (reg0) and edge j+32 (reg1)
    int   s0r = 0, s1r = 0;
    float w0r = 0.f, w1r = 0.f;
    if (hl < cnt) {
        s0r = (int)bucket[node * CAP + hl];
        w0r = rsqrtf((float)cnt_[s0r] + 1.0f) * dn;
    }
    if (hl + 32 < cnt) {
        s1r = (int)bucket[node * CAP + 32 + hl];
        w1r = rsqrtf((float)cnt_[s1r] + 1.0f) * dn;
    }

    // self-loop term (norm_ii = 1/deg = dn*dn)
    float sl = dn * dn;
    bf16x8 hv = *(const bf16x8*)(Hs + (size_t)node * D + col);
    float a[8];
#pragma unroll
    for (int p = 0; p < 8; ++p) a[p] = bf2f((unsigned short)hv[p]) * sl;

    const int cnt0 = cnt < 32 ? cnt : 32;
    int j = 0;
    for (; j + 3 < cnt0; j += 4) {
        int t0 = __shfl(s0r, bb + j,     64), t1 = __shfl(s0r, bb + j + 1, 64);
        int t2 = __shfl(s0r, bb + j + 2, 64), t3 = __shfl(s0r, bb + j + 3, 64);
        float w0 = __shfl(w0r, bb + j,     64), w1 = __shfl(w0r, bb + j + 1, 64);
        float w2 = __shfl(w0r, bb + j + 2, 64), w3 = __shfl(w0r, bb + j + 3, 64);
        bf16x8 u0 = *(const bf16x8*)(Hs + (size_t)t0 * D + col);
        bf16x8 u1 = *(const bf16x8*)(Hs + (size_t)t1 * D + col);
        bf16x8 u2 = *(const bf16x8*)(Hs + (size_t)t2 * D + col);
        bf16x8 u3 = *(const bf16x8*)(Hs + (size_t)t3 * D + col);
#pragma unroll
        for (int p = 0; p < 8; ++p) a[p] = fmaf(bf2f((unsigned short)u0[p]), w0, a[p]);
#pragma unroll
        for (int p = 0; p < 8; ++p) a[p] = fmaf(bf2f((unsigned short)u1[p]), w1, a[p]);
#pragma unroll
        for (int p = 0; p < 8; ++p) a[p] = fmaf(bf2f((unsigned short)u2[p]), w2, a[p]);
#pragma unroll
        for (int p = 0; p < 8; ++p) a[p] = fmaf(bf2f((unsigned short)u3[p]), w3, a[p]);
    }
    for (; j < cnt0; ++j) {
        int   t0 = __shfl(s0r, bb + j, 64);
        float w0 = __shfl(w0r, bb + j, 64);
        bf16x8 u0 = *(const bf16x8*)(Hs + (size_t)t0 * D + col);
#pragma unroll
        for (int p = 0; p < 8; ++p) a[p] = fmaf(bf2f((unsigned short)u0[p]), w0, a[p]);
    }
    if (cnt > 32) {               // Poisson(16) tail: rare
        for (int j2 = 0; j2 < cnt - 32; ++j2) {
            int   t0 = __shfl(s1r, bb + j2, 64);
            float w0 = __shfl(w1r, bb + j2, 64);
            bf16x8 u0 = *(const bf16x8*)(Hs + (size_t)t0 * D + col);
#pragma unroll
            for (int p = 0; p < 8; ++p) a[p] = fmaf(bf2f((unsigned short)u0[p]), w0, a[p]);
        }
    }

    // Z row -> LDS (relu + b1, bf16-rounded exactly as the old Z store)
    {
        float4 b0 = *(const float4*)(bias + col);
        float4 b1v = *(const float4*)(bias + col + 4);
        float bf[8] = {b0.x, b0.y, b0.z, b0.w, b1v.x, b1v.y, b1v.z, b1v.w};
        bf16x8 o;
#pragma unroll
        for (int p = 0; p < 8; ++p) o[p] = (short)f2bf(fmaxf(a[p] + bf[p], 0.f));
        *(bf16x8*)&Zs[lrow * ZLD + col] = o;
    }
    __syncthreads();

    // mini-GEMM: T[8,256] = Zs[8,256] @ Wc_hi^T-layout[256n][256k]
    // wave w covers cols w*64..w*64+63 (4 nt tiles); rows: m_&7 (8 real)
    const int m_ = lane & 15, q = lane >> 4;
    const int wv = t >> 6;
    f32x4 tacc[4];
    const f32x4 zf = {0.f, 0.f, 0.f, 0.f};
#pragma unroll
    for (int nt = 0; nt < 4; ++nt) tacc[nt] = zf;
#pragma unroll
    for (int ks = 0; ks < 8; ++ks) {
        bf16x8 ah = *(const bf16x8*)&Zs[(m_ & 7) * ZLD + ks * 32 + q * 8];
#pragma unroll
        for (int nt = 0; nt < 4; ++nt) {
            int n = wv * 64 + nt * 16 + m_;
            bf16x8 bh = *(const bf16x8*)(Wch + n * 256 + ks * 32 + q * 8);
            tacc[nt] = __builtin_amdgcn_mfma_f32_16x16x32_bf16(ah, bh, tacc[nt], 0, 0, 0);
        }
    }
    // store: C/D layout col=m_, row=q*4+r; rows 0-7 valid (q<2)
    if (q < 2) {
#pragma unroll
        for (int r = 0; r < 4; ++r) {
            int row = q * 4 + r;
            unsigned short* Tp = Tout + (size_t)(nb0 + row) * 256;
#pragma unroll
            for (int nt = 0; nt < 4; ++nt) {
                int gcol = wv * 64 + nt * 16 + m_;
                Tp[gcol] = f2bf(tacc[nt][r]);
            }
        }
    }
}

// Final gather: [mu|lv] = P.T + bcat -> fp32, split at col 128.
// [inner loop verified at the random-gather L2-miss-path floor (~3 TB/s)
// across r1-r11.]
__global__ __launch_bounds__(256) void gather_out(
    const unsigned short* __restrict__ Hs,
    const unsigned short* __restrict__ bucket, const int* __restrict__ cnt_,
    const float* __restrict__ bias,
    float* __restrict__ mu, float* __restrict__ lv)
{
    const int lane = threadIdx.x & 63;
    const int hl = lane & 31;
    const int bb = lane & 32;
    const int node = blockIdx.x * 8 + (threadIdx.x >> 5);
    const int col = hl * 8;
    int raw = cnt_[node];
    float dn = rsqrtf((float)raw + 1.0f);
    int cnt = raw > CAP ? CAP : raw;

    int   s0r = 0, s1r = 0;
    float w0r = 0.f, w1r = 0.f;
    if (hl < cnt) {
        s0r = (int)bucket[node * CAP + hl];
        w0r = rsqrtf((float)cnt_[s0r] + 1.0f) * dn;
    }
    if (hl + 32 < cnt) {
        s1r = (int)bucket[node * CAP + 32 + hl];
        w1r = rsqrtf((float)cnt_[s1r] + 1.0f) * dn;
    }

    float sl = dn * dn;
    bf16x8 hv = *(const bf16x8*)(Hs + (size_t)node * D + col);
    float a[8];
#pragma unroll
    for (int p = 0; p < 8; ++p) a[p] = bf2f((unsigned short)hv[p]) * sl;

    const int cnt0 = cnt < 32 ? cnt : 32;
    int j = 0;
    for (; j + 3 < cnt0; j += 4) {
        int t0 = __shfl(s0r, bb + j,     64), t1 = __shfl(s0r, bb + j + 1, 64);
        int t2 = __shfl(s0r, bb + j + 2, 64), t3 = __shfl(s0r, bb + j + 3, 64);
        float w0 = __shfl(w0r, bb + j,     64), w1 = __shfl(w0r, bb + j + 1, 64);
        float w2 = __shfl(w0r, bb + j + 2, 64), w3 = __shfl(w0r, bb + j + 3, 64);
        bf16x8 u0 = *(const bf16x8*)(Hs + (size_t)t0 * D + col);
        bf16x8 u1 = *(const bf16x8*)(Hs + (size_t)t1 * D + col);
        bf16x8 u2 = *(const bf16x8*)(Hs + (size_t)t2 * D + col);
        bf16x8 u3 = *(const bf16x8*)(Hs + (size_t)t3 * D + col);
#pragma unroll
        for (int p = 0; p < 8; ++p) a[p] = fmaf(bf2f((unsigned short)u0[p]), w0, a[p]);
#pragma unroll
        for (int p = 0; p < 8; ++p) a[p] = fmaf(bf2f((unsigned short)u1[p]), w1, a[p]);
#pragma unroll
        for (int p = 0; p < 8; ++p) a[p] = fmaf(bf2f((unsigned short)u2[p]), w2, a[p]);
#pragma unroll
        for (int p = 0; p < 8; ++p) a[p] = fmaf(bf2f((unsigned short)u3[p]), w3, a[p]);
    }
    for (; j < cnt0; ++j) {
        int   t0 = __shfl(s0r, bb + j, 64);
        float w0 = __shfl(w0r, bb + j, 64);
        bf16x8 u0 = *(const bf16x8*)(Hs + (size_t)t0 * D + col);
#pragma unroll
        for (int p = 0; p < 8; ++p) a[p] = fmaf(bf2f((unsigned short)u0[p]), w0, a[p]);
    }
    if (cnt > 32) {
        for (int j2 = 0; j2 < cnt - 32; ++j2) {
            int   t0 = __shfl(s1r, bb + j2, 64);
            float w0 = __shfl(w1r, bb + j2, 64);
            bf16x8 u0 = *(const bf16x8*)(Hs + (size_t)t0 * D + col);
#pragma unroll
            for (int p = 0; p < 8; ++p) a[p] = fmaf(bf2f((unsigned short)u0[p]), w0, a[p]);
        }
    }

    float4 b0 = *(const float4*)(bias + col);
    float4 b1 = *(const float4*)(bias + col + 4);
    float o0x = a[0] + b0.x, o0y = a[1] + b0.y, o0z = a[2] + b0.z, o0w = a[3] + b0.w;
    float o1x = a[4] + b1.x, o1y = a[5] + b1.y, o1z = a[6] + b1.z, o1w = a[7] + b1.w;
    float4 o0 = {o0x, o0y, o0z, o0w};
    float4 o1 = {o1x, o1y, o1z, o1w};
    float* Op = (col < 128) ? (mu + (size_t)node * L + col)
                            : (lv + (size_t)node * L + (col - 128));
    *(float4*)Op = o0;
    *(float4*)(Op + 4) = o1;
}

extern "C" void kernel_launch(void* const* d_in, const int* in_sizes, int n_in,
                              void* d_out, int out_size, void* d_ws, size_t ws_size,
                              hipStream_t stream) {
    const float* x   = (const float*)d_in[0];
    const int*   ei  = (const int*)d_in[1];
    const float* W1  = (const float*)d_in[2];
    const float* b1  = (const float*)d_in[3];
    const float* Wmu = (const float*)d_in[4];
    const float* bmu = (const float*)d_in[5];
    const float* Wlv = (const float*)d_in[6];
    const float* blv = (const float*)d_in[7];
    const int* src = ei;
    const int* dst = ei + E_EDGES;

    const size_t NF = (size_t)N_NODES * D;  // 12.8M
    unsigned short* Hb = (unsigned short*)d_ws;   // [N,256] bf16
    unsigned short* T  = Hb + NF;                 // [N,256] bf16 = Z @ Wc_hi
    unsigned short* W1h = T + NF;
    unsigned short* W1l = W1h + 65536;
    unsigned short* Wch = W1l + 65536;
    unsigned short* bucket = Wch + 65536;         // [N*CAP] ushort (6.4 MB)
    float* bcat = (float*)(bucket + (size_t)N_NODES * CAP);
    int* cursor = (int*)(bcat + 256);
    float* mu = (float*)d_out;
    float* lv = mu + (size_t)N_NODES * L;

    // setup: tiled weight transpose/split + cursor zeroing in one launch
    setup_t<<<128 + (N_NODES + 255) / 256, 256, 0, stream>>>(
        W1, Wmu, Wlv, bmu, blv, W1h, W1l, Wch, bcat, cursor);

    // fused: H = X@W1 (391 GEMM blocks) + bucket build (3125 fill blocks)
    gemm1_fill<<<3516, 256, 0, stream>>>(x, W1h, W1l, Hb, N_NODES,
                                         src, dst, cursor, bucket);

    const int gat_blocks = N_NODES / 8;              // 6250
    // fused: Z = relu(P·H + b1) in LDS, T = Z @ Wc_hi -> global
    gather_gemm<<<gat_blocks, 256, 0, stream>>>(Hb, bucket, cursor, b1,
                                                Wch, T);
    // [mu|lv] = P·T + [bmu|blv]
    gather_out<<<gat_blocks, 256, 0, stream>>>(T, bucket, cursor, bcat,
                                               mu, lv);
}